// Round 1
// baseline (6123.198 us; speedup 1.0000x reference)
//
#include <hip/hip_runtime.h>
#include <hip/hip_bf16.h>

#define NN 100000
#define DD 128

// ---------------------------------------------------------------------------
// Generic layer GEMM: out[N x 128] = act( A @ W1 [+ (B/deg) @ W2] + bias )
// Block = 256 threads, 32 rows per block. A/B tiles staged in LDS,
// W rows read from global (64KB, L1/L2-resident, coalesced float4).
// Each thread: 4 rows x 4 cols register tile.
// ---------------------------------------------------------------------------
template <bool RELU, bool TWO>
__global__ __launch_bounds__(256) void gemm_layer(
    const float* __restrict__ A, const float* __restrict__ Bm,
    const float* __restrict__ deg,
    const float* __restrict__ W1, const float* __restrict__ W2,
    const float* __restrict__ bias, float* __restrict__ out)
{
    __shared__ float At[32 * 128];
    __shared__ float Bt[TWO ? 32 * 128 : 4];

    const int tid  = threadIdx.x;
    const int row0 = blockIdx.x * 32;

    // Cooperative load of A tile (and scaled B tile): 1024 float4s / 256 thr
#pragma unroll
    for (int i = 0; i < 4; ++i) {
        int f  = tid + i * 256;      // float4 index
        int r  = f >> 5;             // row in tile
        int c4 = (f & 31) << 2;      // col
        float4 av = *(const float4*)(A + (size_t)(row0 + r) * DD + c4);
        *(float4*)(&At[r * DD + c4]) = av;
        if constexpr (TWO) {
            float rd = 1.0f / fmaxf(deg[row0 + r], 1.0f);
            float4 bv = *(const float4*)(Bm + (size_t)(row0 + r) * DD + c4);
            bv.x *= rd; bv.y *= rd; bv.z *= rd; bv.w *= rd;
            *(float4*)(&Bt[r * DD + c4]) = bv;
        }
    }
    __syncthreads();

    const int tx = tid & 31;   // column group: cols 4*tx .. 4*tx+3
    const int ty = tid >> 5;   // row group:   rows 4*ty .. 4*ty+3

    float4 acc[4];
#pragma unroll
    for (int r = 0; r < 4; ++r) acc[r] = make_float4(0.f, 0.f, 0.f, 0.f);

    const float4* W1v = (const float4*)W1;   // W1v[k*32 + tx] = W1[k][4tx..]

#pragma unroll 4
    for (int k = 0; k < DD; k += 4) {
        float4 w0 = W1v[(k + 0) * 32 + tx];
        float4 w1 = W1v[(k + 1) * 32 + tx];
        float4 w2 = W1v[(k + 2) * 32 + tx];
        float4 w3 = W1v[(k + 3) * 32 + tx];
#pragma unroll
        for (int r = 0; r < 4; ++r) {
            float4 a = *(const float4*)(&At[(4 * ty + r) * DD + k]);
            acc[r].x += a.x * w0.x + a.y * w1.x + a.z * w2.x + a.w * w3.x;
            acc[r].y += a.x * w0.y + a.y * w1.y + a.z * w2.y + a.w * w3.y;
            acc[r].z += a.x * w0.z + a.y * w1.z + a.z * w2.z + a.w * w3.z;
            acc[r].w += a.x * w0.w + a.y * w1.w + a.z * w2.w + a.w * w3.w;
        }
    }

    if constexpr (TWO) {
        const float4* W2v = (const float4*)W2;
#pragma unroll 4
        for (int k = 0; k < DD; k += 4) {
            float4 w0 = W2v[(k + 0) * 32 + tx];
            float4 w1 = W2v[(k + 1) * 32 + tx];
            float4 w2 = W2v[(k + 2) * 32 + tx];
            float4 w3 = W2v[(k + 3) * 32 + tx];
#pragma unroll
            for (int r = 0; r < 4; ++r) {
                float4 a = *(const float4*)(&Bt[(4 * ty + r) * DD + k]);
                acc[r].x += a.x * w0.x + a.y * w1.x + a.z * w2.x + a.w * w3.x;
                acc[r].y += a.x * w0.y + a.y * w1.y + a.z * w2.y + a.w * w3.y;
                acc[r].z += a.x * w0.z + a.y * w1.z + a.z * w2.z + a.w * w3.z;
                acc[r].w += a.x * w0.w + a.y * w1.w + a.z * w2.w + a.w * w3.w;
            }
        }
    }

    float4 bv = *(const float4*)(bias + 4 * tx);
#pragma unroll
    for (int r = 0; r < 4; ++r) {
        float4 o;
        o.x = acc[r].x + bv.x;
        o.y = acc[r].y + bv.y;
        o.z = acc[r].z + bv.z;
        o.w = acc[r].w + bv.w;
        if constexpr (RELU) {
            o.x = fmaxf(o.x, 0.f); o.y = fmaxf(o.y, 0.f);
            o.z = fmaxf(o.z, 0.f); o.w = fmaxf(o.w, 0.f);
        }
        *(float4*)(out + (size_t)(row0 + 4 * ty + r) * DD + 4 * tx) = o;
    }
}

// ---------------------------------------------------------------------------
// Edge aggregation: agg[dst] += h[src]; deg[dst] += 1.  32 lanes per edge,
// float4 per lane. agg/deg must be pre-zeroed.
// ---------------------------------------------------------------------------
__global__ __launch_bounds__(256) void scatter_mean(
    const float* __restrict__ h, const int* __restrict__ src,
    const int* __restrict__ dst, float* __restrict__ agg,
    float* __restrict__ deg, int E)
{
    int gid = blockIdx.x * 256 + threadIdx.x;
    int e = gid >> 5;
    if (e >= E) return;
    int lane = gid & 31;
    int s = src[e], d = dst[e];
    float4 v = *(const float4*)(h + (size_t)s * DD + lane * 4);
    float* ap = agg + (size_t)d * DD + lane * 4;
    atomicAdd(ap + 0, v.x);
    atomicAdd(ap + 1, v.y);
    atomicAdd(ap + 2, v.z);
    atomicAdd(ap + 3, v.w);
    if (lane == 0) atomicAdd(deg + d, 1.0f);
}

// ---------------------------------------------------------------------------
// Edge scoring: out[e] = dot(h[src[e]], h[dst[e]]).  32 lanes per edge.
// ---------------------------------------------------------------------------
__global__ __launch_bounds__(256) void score_kernel(
    const float* __restrict__ h, const int* __restrict__ src,
    const int* __restrict__ dst, float* __restrict__ out, int E)
{
    int gid = blockIdx.x * 256 + threadIdx.x;
    int e = gid >> 5;
    if (e >= E) return;
    int lane = gid & 31;
    const float4 a = *(const float4*)(h + (size_t)src[e] * DD + lane * 4);
    const float4 b = *(const float4*)(h + (size_t)dst[e] * DD + lane * 4);
    float s = a.x * b.x + a.y * b.y + a.z * b.z + a.w * b.w;
#pragma unroll
    for (int off = 16; off; off >>= 1) s += __shfl_down(s, off, 32);
    if (lane == 0) out[e] = s;
}

extern "C" void kernel_launch(void* const* d_in, const int* in_sizes, int n_in,
                              void* d_out, int out_size, void* d_ws, size_t ws_size,
                              hipStream_t stream)
{
    const float* feat    = (const float*)d_in[0];
    const int*   e0s     = (const int*)d_in[1];
    const int*   e0d     = (const int*)d_in[2];
    const int*   e1s     = (const int*)d_in[3];
    const int*   e1d     = (const int*)d_in[4];
    const int*   ps      = (const int*)d_in[5];
    const int*   pd      = (const int*)d_in[6];
    const int*   ns      = (const int*)d_in[7];
    const int*   nd      = (const int*)d_in[8];
    const float* w_proj  = (const float*)d_in[9];
    const float* b_proj  = (const float*)d_in[10];
    const float* w_self1 = (const float*)d_in[11];
    const float* w_neigh1= (const float*)d_in[12];
    const float* b1      = (const float*)d_in[13];
    const float* w_self2 = (const float*)d_in[14];
    const float* w_neigh2= (const float*)d_in[15];
    const float* b2      = (const float*)d_in[16];

    float* out = (float*)d_out;

    const size_t NF = (size_t)NN * DD;
    float* B0  = (float*)d_ws;       // h1, later agg2
    float* B1  = B0 + NF;            // agg1, later h3
    float* B2  = B1 + NF;            // h2
    float* deg = B2 + NF;            // [NN]

    const int E0 = in_sizes[1];
    const int E1 = in_sizes[3];
    const int EP = in_sizes[5];
    const int EN = in_sizes[7];

    // ---- Layer 0: projection  h1 = relu(feat @ w_proj + b_proj) -> B0
    hipMemsetAsync(B1, 0, NF * sizeof(float), stream);
    hipMemsetAsync(deg, 0, NN * sizeof(float), stream);
    gemm_layer<true, false><<<NN / 32, 256, 0, stream>>>(
        feat, nullptr, nullptr, w_proj, nullptr, b_proj, B0);

    // ---- Layer 1 aggregation + GEMM -> B2
    scatter_mean<<<(E0 * 32 + 255) / 256, 256, 0, stream>>>(B0, e0s, e0d, B1, deg, E0);
    gemm_layer<true, true><<<NN / 32, 256, 0, stream>>>(
        B0, B1, deg, w_self1, w_neigh1, b1, B2);

    // ---- Layer 2 aggregation + GEMM -> B1 (h3)
    hipMemsetAsync(B0, 0, NF * sizeof(float), stream);
    hipMemsetAsync(deg, 0, NN * sizeof(float), stream);
    scatter_mean<<<(E1 * 32 + 255) / 256, 256, 0, stream>>>(B2, e1s, e1d, B0, deg, E1);
    gemm_layer<false, true><<<NN / 32, 256, 0, stream>>>(
        B2, B0, deg, w_self2, w_neigh2, b2, B1);

    // ---- Scoring
    score_kernel<<<(EP * 32 + 255) / 256, 256, 0, stream>>>(B1, ps, pd, out, EP);
    score_kernel<<<(EN * 32 + 255) / 256, 256, 0, stream>>>(B1, ns, nd, out + EP, EN);
}

// Round 2
// 1207.255 us; speedup vs baseline: 5.0720x; 5.0720x over previous
//
#include <hip/hip_runtime.h>
#include <hip/hip_bf16.h>

#define NN 100000
#define DD 128

// ---------------------------------------------------------------------------
// Layer GEMM: out[N x 128] = act( A @ W1 [+ (B/deg) @ W2] + bias )
// Block = 256 threads, 32 rows per block, 4x4 register tile per thread.
// deg comes from the CSR counts (int).
// ---------------------------------------------------------------------------
template <bool RELU, bool TWO>
__global__ __launch_bounds__(256) void gemm_layer(
    const float* __restrict__ A, const float* __restrict__ Bm,
    const int* __restrict__ counts,
    const float* __restrict__ W1, const float* __restrict__ W2,
    const float* __restrict__ bias, float* __restrict__ out)
{
    __shared__ float At[32 * 128];
    __shared__ float Bt[TWO ? 32 * 128 : 4];

    const int tid  = threadIdx.x;
    const int row0 = blockIdx.x * 32;

#pragma unroll
    for (int i = 0; i < 4; ++i) {
        int f  = tid + i * 256;      // float4 index
        int r  = f >> 5;             // row in tile
        int c4 = (f & 31) << 2;      // col
        float4 av = *(const float4*)(A + (size_t)(row0 + r) * DD + c4);
        *(float4*)(&At[r * DD + c4]) = av;
        if constexpr (TWO) {
            float rd = 1.0f / fmaxf((float)counts[row0 + r], 1.0f);
            float4 bv = *(const float4*)(Bm + (size_t)(row0 + r) * DD + c4);
            bv.x *= rd; bv.y *= rd; bv.z *= rd; bv.w *= rd;
            *(float4*)(&Bt[r * DD + c4]) = bv;
        }
    }
    __syncthreads();

    const int tx = tid & 31;   // cols 4*tx .. 4*tx+3
    const int ty = tid >> 5;   // rows 4*ty .. 4*ty+3

    float4 acc[4];
#pragma unroll
    for (int r = 0; r < 4; ++r) acc[r] = make_float4(0.f, 0.f, 0.f, 0.f);

    const float4* W1v = (const float4*)W1;

#pragma unroll 4
    for (int k = 0; k < DD; k += 4) {
        float4 w0 = W1v[(k + 0) * 32 + tx];
        float4 w1 = W1v[(k + 1) * 32 + tx];
        float4 w2 = W1v[(k + 2) * 32 + tx];
        float4 w3 = W1v[(k + 3) * 32 + tx];
#pragma unroll
        for (int r = 0; r < 4; ++r) {
            float4 a = *(const float4*)(&At[(4 * ty + r) * DD + k]);
            acc[r].x += a.x * w0.x + a.y * w1.x + a.z * w2.x + a.w * w3.x;
            acc[r].y += a.x * w0.y + a.y * w1.y + a.z * w2.y + a.w * w3.y;
            acc[r].z += a.x * w0.z + a.y * w1.z + a.z * w2.z + a.w * w3.z;
            acc[r].w += a.x * w0.w + a.y * w1.w + a.z * w2.w + a.w * w3.w;
        }
    }

    if constexpr (TWO) {
        const float4* W2v = (const float4*)W2;
#pragma unroll 4
        for (int k = 0; k < DD; k += 4) {
            float4 w0 = W2v[(k + 0) * 32 + tx];
            float4 w1 = W2v[(k + 1) * 32 + tx];
            float4 w2 = W2v[(k + 2) * 32 + tx];
            float4 w3 = W2v[(k + 3) * 32 + tx];
#pragma unroll
            for (int r = 0; r < 4; ++r) {
                float4 a = *(const float4*)(&Bt[(4 * ty + r) * DD + k]);
                acc[r].x += a.x * w0.x + a.y * w1.x + a.z * w2.x + a.w * w3.x;
                acc[r].y += a.x * w0.y + a.y * w1.y + a.z * w2.y + a.w * w3.y;
                acc[r].z += a.x * w0.z + a.y * w1.z + a.z * w2.z + a.w * w3.z;
                acc[r].w += a.x * w0.w + a.y * w1.w + a.z * w2.w + a.w * w3.w;
            }
        }
    }

    float4 bv = *(const float4*)(bias + 4 * tx);
#pragma unroll
    for (int r = 0; r < 4; ++r) {
        float4 o;
        o.x = acc[r].x + bv.x;
        o.y = acc[r].y + bv.y;
        o.z = acc[r].z + bv.z;
        o.w = acc[r].w + bv.w;
        if constexpr (RELU) {
            o.x = fmaxf(o.x, 0.f); o.y = fmaxf(o.y, 0.f);
            o.z = fmaxf(o.z, 0.f); o.w = fmaxf(o.w, 0.f);
        }
        *(float4*)(out + (size_t)(row0 + 4 * ty + r) * DD + 4 * tx) = o;
    }
}

// ---------------------------------------------------------------------------
// CSR build
// ---------------------------------------------------------------------------
__global__ __launch_bounds__(256) void count_kernel(
    const int* __restrict__ dst, int* __restrict__ counts, int E)
{
    int e = blockIdx.x * 256 + threadIdx.x;
    if (e < E) atomicAdd(&counts[dst[e]], 1);
}

// scan phase 1: per-block (1024 elems) exclusive scan, in-place into offs
__global__ __launch_bounds__(256) void scan1(
    const int* __restrict__ counts, int* __restrict__ offs,
    int* __restrict__ partials, int n)
{
    __shared__ int lds[256];
    const int tid  = threadIdx.x;
    const int base = blockIdx.x * 1024 + tid * 4;
    int v[4], s = 0;
#pragma unroll
    for (int i = 0; i < 4; ++i) {
        v[i] = (base + i < n) ? counts[base + i] : 0;
        s += v[i];
    }
    lds[tid] = s;
    __syncthreads();
    for (int off = 1; off < 256; off <<= 1) {
        int t = 0;
        if (tid >= off) t = lds[tid - off];
        __syncthreads();
        if (tid >= off) lds[tid] += t;
        __syncthreads();
    }
    int run = lds[tid] - s;   // exclusive prefix of this thread
#pragma unroll
    for (int i = 0; i < 4; ++i) {
        if (base + i < n) offs[base + i] = run;
        run += v[i];
    }
    if (tid == 255) partials[blockIdx.x] = lds[255];
}

// scan phase 2: single block exclusive scan of block partials (nb <= 128)
__global__ __launch_bounds__(128) void scan2(int* __restrict__ partials, int nb)
{
    __shared__ int lds[128];
    const int tid = threadIdx.x;
    int v = (tid < nb) ? partials[tid] : 0;
    lds[tid] = v;
    __syncthreads();
    for (int off = 1; off < 128; off <<= 1) {
        int t = 0;
        if (tid >= off) t = lds[tid - off];
        __syncthreads();
        if (tid >= off) lds[tid] += t;
        __syncthreads();
    }
    if (tid < nb) partials[tid] = lds[tid] - v;
}

// scan phase 3: add block offset, produce final offsets + cursor copy
__global__ __launch_bounds__(256) void scan3(
    int* __restrict__ offs, int* __restrict__ cursor,
    const int* __restrict__ partials, int n)
{
    int i = blockIdx.x * 256 + threadIdx.x;
    if (i < n) {
        int o = offs[i] + partials[i >> 10];
        offs[i]   = o;
        cursor[i] = o;
    }
}

__global__ __launch_bounds__(256) void fill_kernel(
    const int* __restrict__ src, const int* __restrict__ dst,
    int* __restrict__ cursor, int* __restrict__ csr, int E)
{
    int e = blockIdx.x * 256 + threadIdx.x;
    if (e < E) {
        int pos = atomicAdd(&cursor[dst[e]], 1);
        csr[pos] = src[e];
    }
}

// ---------------------------------------------------------------------------
// CSR aggregation: agg[n] = sum over incoming src of h[src].
// 32 lanes per node, float4 per lane, register accumulation. No atomics.
// ---------------------------------------------------------------------------
__global__ __launch_bounds__(256) void aggregate(
    const float* __restrict__ h, const int* __restrict__ csr,
    const int* __restrict__ offs, const int* __restrict__ counts,
    float* __restrict__ agg, int nn)
{
    int gid  = blockIdx.x * 256 + threadIdx.x;
    int node = gid >> 5;
    if (node >= nn) return;
    int lane  = gid & 31;
    int start = offs[node];
    int cnt   = counts[node];

    float4 acc = make_float4(0.f, 0.f, 0.f, 0.f);
    int j = 0;
    for (; j + 4 <= cnt; j += 4) {
        int s0 = csr[start + j + 0];
        int s1 = csr[start + j + 1];
        int s2 = csr[start + j + 2];
        int s3 = csr[start + j + 3];
        float4 v0 = *(const float4*)(h + (size_t)s0 * DD + lane * 4);
        float4 v1 = *(const float4*)(h + (size_t)s1 * DD + lane * 4);
        float4 v2 = *(const float4*)(h + (size_t)s2 * DD + lane * 4);
        float4 v3 = *(const float4*)(h + (size_t)s3 * DD + lane * 4);
        acc.x += v0.x + v1.x + v2.x + v3.x;
        acc.y += v0.y + v1.y + v2.y + v3.y;
        acc.z += v0.z + v1.z + v2.z + v3.z;
        acc.w += v0.w + v1.w + v2.w + v3.w;
    }
    for (; j < cnt; ++j) {
        int s = csr[start + j];
        float4 v = *(const float4*)(h + (size_t)s * DD + lane * 4);
        acc.x += v.x; acc.y += v.y; acc.z += v.z; acc.w += v.w;
    }
    *(float4*)(agg + (size_t)node * DD + lane * 4) = acc;
}

// ---------------------------------------------------------------------------
// Edge scoring: out[e] = dot(h[src[e]], h[dst[e]]).  32 lanes per edge.
// ---------------------------------------------------------------------------
__global__ __launch_bounds__(256) void score_kernel(
    const float* __restrict__ h, const int* __restrict__ src,
    const int* __restrict__ dst, float* __restrict__ out, int E)
{
    int gid = blockIdx.x * 256 + threadIdx.x;
    int e = gid >> 5;
    if (e >= E) return;
    int lane = gid & 31;
    const float4 a = *(const float4*)(h + (size_t)src[e] * DD + lane * 4);
    const float4 b = *(const float4*)(h + (size_t)dst[e] * DD + lane * 4);
    float s = a.x * b.x + a.y * b.y + a.z * b.z + a.w * b.w;
#pragma unroll
    for (int off = 16; off; off >>= 1) s += __shfl_down(s, off, 32);
    if (lane == 0) out[e] = s;
}

// ---------------------------------------------------------------------------

static void build_csr_and_aggregate(const float* h, const int* esrc, const int* edst,
                                    int E, int* counts, int* scratch /* >= 2*NN+128+E ints */,
                                    float* agg, hipStream_t stream)
{
    int* offs     = scratch;                 // [NN]
    int* cursor   = scratch + NN;            // [NN]
    int* partials = scratch + 2 * NN;        // [128]
    int* csr      = scratch + 2 * NN + 128;  // [E]

    const int NB = (NN + 1023) / 1024;       // 98

    hipMemsetAsync(counts, 0, NN * sizeof(int), stream);
    count_kernel<<<(E + 255) / 256, 256, 0, stream>>>(edst, counts, E);
    scan1<<<NB, 256, 0, stream>>>(counts, offs, partials, NN);
    scan2<<<1, 128, 0, stream>>>(partials, NB);
    scan3<<<(NN + 255) / 256, 256, 0, stream>>>(offs, cursor, partials, NN);
    fill_kernel<<<(E + 255) / 256, 256, 0, stream>>>(esrc, edst, cursor, csr, E);
    aggregate<<<(NN * 32 + 255) / 256, 256, 0, stream>>>(h, csr, offs, counts, agg, NN);
}

extern "C" void kernel_launch(void* const* d_in, const int* in_sizes, int n_in,
                              void* d_out, int out_size, void* d_ws, size_t ws_size,
                              hipStream_t stream)
{
    const float* feat    = (const float*)d_in[0];
    const int*   e0s     = (const int*)d_in[1];
    const int*   e0d     = (const int*)d_in[2];
    const int*   e1s     = (const int*)d_in[3];
    const int*   e1d     = (const int*)d_in[4];
    const int*   ps      = (const int*)d_in[5];
    const int*   pd      = (const int*)d_in[6];
    const int*   ns      = (const int*)d_in[7];
    const int*   nd      = (const int*)d_in[8];
    const float* w_proj  = (const float*)d_in[9];
    const float* b_proj  = (const float*)d_in[10];
    const float* w_self1 = (const float*)d_in[11];
    const float* w_neigh1= (const float*)d_in[12];
    const float* b1      = (const float*)d_in[13];
    const float* w_self2 = (const float*)d_in[14];
    const float* w_neigh2= (const float*)d_in[15];
    const float* b2      = (const float*)d_in[16];

    float* out = (float*)d_out;

    const size_t NF = (size_t)NN * DD;
    float* B0     = (float*)d_ws;   // h1, later (csr2 scratch, then h3)
    float* B1     = B0 + NF;        // agg1, later agg2
    float* B2     = B1 + NF;        // (csr1 scratch), then h2
    int*   counts = (int*)(B2 + NF);// [NN] — live into the GEMM (deg)

    const int E0 = in_sizes[1];
    const int E1 = in_sizes[3];
    const int EP = in_sizes[5];
    const int EN = in_sizes[7];

    // ---- Layer 0: h1 = relu(feat @ w_proj + b_proj) -> B0
    gemm_layer<true, false><<<NN / 32, 256, 0, stream>>>(
        feat, nullptr, nullptr, w_proj, nullptr, b_proj, B0);

    // ---- Layer 1: CSR(edge0) in B2 scratch, agg1 -> B1, then GEMM -> B2
    build_csr_and_aggregate(B0, e0s, e0d, E0, counts, (int*)B2, B1, stream);
    gemm_layer<true, true><<<NN / 32, 256, 0, stream>>>(
        B0, B1, counts, w_self1, w_neigh1, b1, B2);

    // ---- Layer 2: CSR(edge1) in B0 scratch, agg2 -> B1, then GEMM -> B0 (h3)
    build_csr_and_aggregate(B2, e1s, e1d, E1, counts, (int*)B0, B1, stream);
    gemm_layer<false, true><<<NN / 32, 256, 0, stream>>>(
        B2, B1, counts, w_self2, w_neigh2, b2, B0);

    // ---- Scoring on h3 = B0
    score_kernel<<<(EP * 32 + 255) / 256, 256, 0, stream>>>(B0, ps, pd, out, EP);
    score_kernel<<<(EN * 32 + 255) / 256, 256, 0, stream>>>(B0, ns, nd, out + EP, EN);
}

// Round 3
// 1114.200 us; speedup vs baseline: 5.4956x; 1.0835x over previous
//
#include <hip/hip_runtime.h>
#include <hip/hip_bf16.h>

#define NN 100000
#define DD 128

typedef __attribute__((address_space(3))) unsigned int lds_uint;
typedef __attribute__((address_space(1))) unsigned int glb_uint;

// ---------------------------------------------------------------------------
// Layer GEMM: out[N x 128] = act( A @ W1 [+ Bm @ W2] + bias )
// (Bm is already the neighbor MEAN — division happens in aggregate.)
// 128x128 tile per 256-thread block; 8 rows x 8 cols per thread; K chunked
// by 32 with LDS staging. Dual case = one K=256 GEMM over [A|Bm]@[W1;W2].
// A tile: stride-40 rows + ty+16r row interleave -> conflict-free b128 reads.
// W tile: linear layout, staged via global_load_lds (16B).
// ---------------------------------------------------------------------------
template <bool RELU, bool TWO>
__global__ __launch_bounds__(256, 3) void gemm_layer(
    const float* __restrict__ A, const float* __restrict__ Bm,
    const float* __restrict__ W1, const float* __restrict__ W2,
    const float* __restrict__ bias, float* __restrict__ out)
{
    __shared__ float At[128 * 40];   // 20.0 KB
    __shared__ float Wt[32 * 128];   // 16.0 KB

    const int tid  = threadIdx.x;
    const int row0 = blockIdx.x * 128;
    const int tx   = tid & 15;       // cols 4tx..4tx+3 and 64+4tx..64+4tx+3
    const int ty   = tid >> 4;       // rows ty+16r, r=0..7

    float4 acc0[8], acc1[8];
#pragma unroll
    for (int r = 0; r < 8; ++r) {
        acc0[r] = make_float4(0.f, 0.f, 0.f, 0.f);
        acc1[r] = make_float4(0.f, 0.f, 0.f, 0.f);
    }

    const int NCH = TWO ? 8 : 4;

#pragma unroll 1
    for (int ch = 0; ch < NCH; ++ch) {
        const bool second = TWO && (ch >= 4);
        const int  kk     = (ch & 3) * 32;
        const float* __restrict__ sp = second ? Bm : A;
        const float* __restrict__ wp = second ? W2 : W1;

        // W chunk 32x128: linear global -> linear LDS, async DMA
#pragma unroll
        for (int j = 0; j < 4; ++j) {
            int g = tid + 256 * j;                       // float4 index
            __builtin_amdgcn_global_load_lds(
                (glb_uint*)(wp + (size_t)kk * DD + g * 4),
                (lds_uint*)(Wt + g * 4), 16, 0, 0);
        }

        // A chunk 128x32 -> LDS with padded stride 40
        float4 av[4];
#pragma unroll
        for (int j = 0; j < 4; ++j) {
            int g  = tid + 256 * j;                      // 0..1023
            int r  = g >> 3;
            int c4 = g & 7;
            int grow = row0 + r;
            if (grow > NN - 1) grow = NN - 1;            // clamp (last block)
            av[j] = *(const float4*)(sp + (size_t)grow * DD + kk + 4 * c4);
        }
#pragma unroll
        for (int j = 0; j < 4; ++j) {
            int g  = tid + 256 * j;
            int r  = g >> 3;
            int c4 = g & 7;
            *(float4*)(&At[r * 40 + 4 * c4]) = av[j];
        }

        __syncthreads();   // drains A stores + W DMA (vmcnt/lgkm)

#pragma unroll 4
        for (int k0 = 0; k0 < 32; k0 += 4) {
            float4 w0[4], w1[4];
#pragma unroll
            for (int j = 0; j < 4; ++j) {
                w0[j] = *(const float4*)(&Wt[(k0 + j) * DD + 4 * tx]);
                w1[j] = *(const float4*)(&Wt[(k0 + j) * DD + 64 + 4 * tx]);
            }
#pragma unroll
            for (int r = 0; r < 8; ++r) {
                float4 a = *(const float4*)(&At[(ty + 16 * r) * 40 + k0]);
                acc0[r].x += a.x*w0[0].x + a.y*w0[1].x + a.z*w0[2].x + a.w*w0[3].x;
                acc0[r].y += a.x*w0[0].y + a.y*w0[1].y + a.z*w0[2].y + a.w*w0[3].y;
                acc0[r].z += a.x*w0[0].z + a.y*w0[1].z + a.z*w0[2].z + a.w*w0[3].z;
                acc0[r].w += a.x*w0[0].w + a.y*w0[1].w + a.z*w0[2].w + a.w*w0[3].w;
                acc1[r].x += a.x*w1[0].x + a.y*w1[1].x + a.z*w1[2].x + a.w*w1[3].x;
                acc1[r].y += a.x*w1[0].y + a.y*w1[1].y + a.z*w1[2].y + a.w*w1[3].y;
                acc1[r].z += a.x*w1[0].z + a.y*w1[1].z + a.z*w1[2].z + a.w*w1[3].z;
                acc1[r].w += a.x*w1[0].w + a.y*w1[1].w + a.z*w1[2].w + a.w*w1[3].w;
            }
        }
        __syncthreads();
    }

    float4 bv0 = *(const float4*)(bias + 4 * tx);
    float4 bv1 = *(const float4*)(bias + 64 + 4 * tx);
#pragma unroll
    for (int r = 0; r < 8; ++r) {
        int row = row0 + ty + 16 * r;
        if (row < NN) {
            float4 o0, o1;
            o0.x = acc0[r].x + bv0.x; o0.y = acc0[r].y + bv0.y;
            o0.z = acc0[r].z + bv0.z; o0.w = acc0[r].w + bv0.w;
            o1.x = acc1[r].x + bv1.x; o1.y = acc1[r].y + bv1.y;
            o1.z = acc1[r].z + bv1.z; o1.w = acc1[r].w + bv1.w;
            if constexpr (RELU) {
                o0.x = fmaxf(o0.x, 0.f); o0.y = fmaxf(o0.y, 0.f);
                o0.z = fmaxf(o0.z, 0.f); o0.w = fmaxf(o0.w, 0.f);
                o1.x = fmaxf(o1.x, 0.f); o1.y = fmaxf(o1.y, 0.f);
                o1.z = fmaxf(o1.z, 0.f); o1.w = fmaxf(o1.w, 0.f);
            }
            *(float4*)(out + (size_t)row * DD + 4 * tx) = o0;
            *(float4*)(out + (size_t)row * DD + 64 + 4 * tx) = o1;
        }
    }
}

// ---------------------------------------------------------------------------
// CSR build
// ---------------------------------------------------------------------------
__global__ __launch_bounds__(256) void count_kernel(
    const int* __restrict__ dst, int* __restrict__ counts, int E)
{
    int e = blockIdx.x * 256 + threadIdx.x;
    if (e < E) atomicAdd(&counts[dst[e]], 1);
}

__global__ __launch_bounds__(256) void scan1(
    const int* __restrict__ counts, int* __restrict__ offs,
    int* __restrict__ partials, int n)
{
    __shared__ int lds[256];
    const int tid  = threadIdx.x;
    const int base = blockIdx.x * 1024 + tid * 4;
    int v[4], s = 0;
#pragma unroll
    for (int i = 0; i < 4; ++i) {
        v[i] = (base + i < n) ? counts[base + i] : 0;
        s += v[i];
    }
    lds[tid] = s;
    __syncthreads();
    for (int off = 1; off < 256; off <<= 1) {
        int t = 0;
        if (tid >= off) t = lds[tid - off];
        __syncthreads();
        if (tid >= off) lds[tid] += t;
        __syncthreads();
    }
    int run = lds[tid] - s;
#pragma unroll
    for (int i = 0; i < 4; ++i) {
        if (base + i < n) offs[base + i] = run;
        run += v[i];
    }
    if (tid == 255) partials[blockIdx.x] = lds[255];
}

__global__ __launch_bounds__(128) void scan2(int* __restrict__ partials, int nb)
{
    __shared__ int lds[128];
    const int tid = threadIdx.x;
    int v = (tid < nb) ? partials[tid] : 0;
    lds[tid] = v;
    __syncthreads();
    for (int off = 1; off < 128; off <<= 1) {
        int t = 0;
        if (tid >= off) t = lds[tid - off];
        __syncthreads();
        if (tid >= off) lds[tid] += t;
        __syncthreads();
    }
    if (tid < nb) partials[tid] = lds[tid] - v;
}

__global__ __launch_bounds__(256) void scan3(
    int* __restrict__ offs, int* __restrict__ cursor,
    const int* __restrict__ partials, int n)
{
    int i = blockIdx.x * 256 + threadIdx.x;
    if (i < n) {
        int o = offs[i] + partials[i >> 10];
        offs[i]   = o;
        cursor[i] = o;
    }
}

__global__ __launch_bounds__(256) void fill_kernel(
    const int* __restrict__ src, const int* __restrict__ dst,
    int* __restrict__ cursor, int* __restrict__ csr, int E)
{
    int e = blockIdx.x * 256 + threadIdx.x;
    if (e < E) {
        int pos = atomicAdd(&cursor[dst[e]], 1);
        csr[pos] = src[e];
    }
}

// ---------------------------------------------------------------------------
// CSR aggregation with mean: agg[n] = (1/max(deg,1)) * sum_{src in N(n)} h[src]
// 32 lanes per node, float4 per lane, register accumulation. No atomics.
// ---------------------------------------------------------------------------
__global__ __launch_bounds__(256) void aggregate(
    const float* __restrict__ h, const int* __restrict__ csr,
    const int* __restrict__ offs, const int* __restrict__ counts,
    float* __restrict__ agg, int nn)
{
    int gid  = blockIdx.x * 256 + threadIdx.x;
    int node = gid >> 5;
    if (node >= nn) return;
    int lane  = gid & 31;
    int start = offs[node];
    int cnt   = counts[node];

    float4 acc = make_float4(0.f, 0.f, 0.f, 0.f);
    int j = 0;
    for (; j + 4 <= cnt; j += 4) {
        int s0 = csr[start + j + 0];
        int s1 = csr[start + j + 1];
        int s2 = csr[start + j + 2];
        int s3 = csr[start + j + 3];
        float4 v0 = *(const float4*)(h + (size_t)s0 * DD + lane * 4);
        float4 v1 = *(const float4*)(h + (size_t)s1 * DD + lane * 4);
        float4 v2 = *(const float4*)(h + (size_t)s2 * DD + lane * 4);
        float4 v3 = *(const float4*)(h + (size_t)s3 * DD + lane * 4);
        acc.x += v0.x + v1.x + v2.x + v3.x;
        acc.y += v0.y + v1.y + v2.y + v3.y;
        acc.z += v0.z + v1.z + v2.z + v3.z;
        acc.w += v0.w + v1.w + v2.w + v3.w;
    }
    for (; j < cnt; ++j) {
        int s = csr[start + j];
        float4 v = *(const float4*)(h + (size_t)s * DD + lane * 4);
        acc.x += v.x; acc.y += v.y; acc.z += v.z; acc.w += v.w;
    }
    float rinv = 1.0f / (float)(cnt > 1 ? cnt : 1);
    acc.x *= rinv; acc.y *= rinv; acc.z *= rinv; acc.w *= rinv;
    *(float4*)(agg + (size_t)node * DD + lane * 4) = acc;
}

// ---------------------------------------------------------------------------
// Edge scoring: out[e] = dot(h[src[e]], h[dst[e]]).  32 lanes per edge.
// ---------------------------------------------------------------------------
__global__ __launch_bounds__(256) void score_kernel(
    const float* __restrict__ h, const int* __restrict__ src,
    const int* __restrict__ dst, float* __restrict__ out, int E)
{
    int gid = blockIdx.x * 256 + threadIdx.x;
    int e = gid >> 5;
    if (e >= E) return;
    int lane = gid & 31;
    const float4 a = *(const float4*)(h + (size_t)src[e] * DD + lane * 4);
    const float4 b = *(const float4*)(h + (size_t)dst[e] * DD + lane * 4);
    float s = a.x * b.x + a.y * b.y + a.z * b.z + a.w * b.w;
#pragma unroll
    for (int off = 16; off; off >>= 1) s += __shfl_down(s, off, 32);
    if (lane == 0) out[e] = s;
}

// ---------------------------------------------------------------------------

static void build_csr_and_aggregate(const float* h, const int* esrc, const int* edst,
                                    int E, int* counts, int* scratch,
                                    float* agg, hipStream_t stream)
{
    int* offs     = scratch;                 // [NN]
    int* cursor   = scratch + NN;            // [NN]
    int* partials = scratch + 2 * NN;        // [128]
    int* csr      = scratch + 2 * NN + 128;  // [E]

    const int NB = (NN + 1023) / 1024;       // 98

    hipMemsetAsync(counts, 0, NN * sizeof(int), stream);
    count_kernel<<<(E + 255) / 256, 256, 0, stream>>>(edst, counts, E);
    scan1<<<NB, 256, 0, stream>>>(counts, offs, partials, NN);
    scan2<<<1, 128, 0, stream>>>(partials, NB);
    scan3<<<(NN + 255) / 256, 256, 0, stream>>>(offs, cursor, partials, NN);
    fill_kernel<<<(E + 255) / 256, 256, 0, stream>>>(esrc, edst, cursor, csr, E);
    aggregate<<<(NN * 32 + 255) / 256, 256, 0, stream>>>(h, csr, offs, counts, agg, NN);
}

extern "C" void kernel_launch(void* const* d_in, const int* in_sizes, int n_in,
                              void* d_out, int out_size, void* d_ws, size_t ws_size,
                              hipStream_t stream)
{
    const float* feat    = (const float*)d_in[0];
    const int*   e0s     = (const int*)d_in[1];
    const int*   e0d     = (const int*)d_in[2];
    const int*   e1s     = (const int*)d_in[3];
    const int*   e1d     = (const int*)d_in[4];
    const int*   ps      = (const int*)d_in[5];
    const int*   pd      = (const int*)d_in[6];
    const int*   ns      = (const int*)d_in[7];
    const int*   nd      = (const int*)d_in[8];
    const float* w_proj  = (const float*)d_in[9];
    const float* b_proj  = (const float*)d_in[10];
    const float* w_self1 = (const float*)d_in[11];
    const float* w_neigh1= (const float*)d_in[12];
    const float* b1      = (const float*)d_in[13];
    const float* w_self2 = (const float*)d_in[14];
    const float* w_neigh2= (const float*)d_in[15];
    const float* b2      = (const float*)d_in[16];

    float* out = (float*)d_out;

    const size_t NF = (size_t)NN * DD;
    float* B0     = (float*)d_ws;   // h1, later (csr2 scratch, then h3)
    float* B1     = B0 + NF;        // mean1, later mean2
    float* B2     = B1 + NF;        // (csr1 scratch), then h2
    int*   counts = (int*)(B2 + NF);// [NN]

    const int E0 = in_sizes[1];
    const int E1 = in_sizes[3];
    const int EP = in_sizes[5];
    const int EN = in_sizes[7];

    const int GB = (NN + 127) / 128;   // gemm blocks

    // ---- Layer 0: h1 = relu(feat @ w_proj + b_proj) -> B0
    gemm_layer<true, false><<<GB, 256, 0, stream>>>(
        feat, nullptr, w_proj, nullptr, b_proj, B0);

    // ---- Layer 1: CSR(edge0) in B2 scratch, mean1 -> B1, GEMM -> B2
    build_csr_and_aggregate(B0, e0s, e0d, E0, counts, (int*)B2, B1, stream);
    gemm_layer<true, true><<<GB, 256, 0, stream>>>(
        B0, B1, w_self1, w_neigh1, b1, B2);

    // ---- Layer 2: CSR(edge1) in B0 scratch, mean2 -> B1, GEMM -> B0 (h3)
    build_csr_and_aggregate(B2, e1s, e1d, E1, counts, (int*)B0, B1, stream);
    gemm_layer<false, true><<<GB, 256, 0, stream>>>(
        B2, B1, w_self2, w_neigh2, b2, B0);

    // ---- Scoring on h3 = B0
    score_kernel<<<(EP * 32 + 255) / 256, 256, 0, stream>>>(B0, ps, pd, out, EP);
    score_kernel<<<(EN * 32 + 255) / 256, 256, 0, stream>>>(B0, ns, nd, out + EP, EN);
}

// Round 4
// 852.691 us; speedup vs baseline: 7.1810x; 1.3067x over previous
//
#include <hip/hip_runtime.h>
#include <hip/hip_bf16.h>

#define NN 100000
#define DD 128

typedef unsigned short ushort_t;
typedef unsigned int uint_t;
typedef __attribute__((ext_vector_type(8))) short bf16x8;
typedef __attribute__((ext_vector_type(4))) float f32x4;

__device__ __forceinline__ ushort_t f2bf(float f) {
    uint_t u = __builtin_bit_cast(uint_t, f);
    u += 0x7FFFu + ((u >> 16) & 1u);          // RNE
    return (ushort_t)(u >> 16);
}
__device__ __forceinline__ uint_t pack2bf(float a, float b) {
    return (uint_t)f2bf(a) | ((uint_t)f2bf(b) << 16);
}
__device__ __forceinline__ float bflo(uint_t v) {   // low ushort -> float
    return __builtin_bit_cast(float, v << 16);
}
__device__ __forceinline__ float bfhi(uint_t v) {   // high ushort -> float
    return __builtin_bit_cast(float, v & 0xFFFF0000u);
}

// ---------------------------------------------------------------------------
// feat fp32 -> bf16, 8 elems/thread
// ---------------------------------------------------------------------------
__global__ __launch_bounds__(256) void convert_feat(
    const float* __restrict__ src, ushort_t* __restrict__ dst)
{
    size_t t = (size_t)blockIdx.x * 256 + threadIdx.x;
    size_t base = t * 8;                      // NN*DD divisible by 8
    float4 a = *(const float4*)(src + base);
    float4 b = *(const float4*)(src + base + 4);
    uint4 o;
    o.x = pack2bf(a.x, a.y); o.y = pack2bf(a.z, a.w);
    o.z = pack2bf(b.x, b.y); o.w = pack2bf(b.z, b.w);
    *(uint4*)(dst + base) = o;
}

// ---------------------------------------------------------------------------
// weight prep: dst[n*Ktot + koff + k] = bf16(src[k*128 + n]);  K = 128 fixed
// ---------------------------------------------------------------------------
__global__ __launch_bounds__(256) void prep_w(
    const float* __restrict__ src, ushort_t* __restrict__ dst,
    int Ktot, int koff)
{
    int t = blockIdx.x * 256 + threadIdx.x;   // 128*128 = 16384
    if (t >= 128 * 128) return;
    int n = t >> 7, k = t & 127;
    dst[(size_t)n * Ktot + koff + k] = f2bf(src[(size_t)k * 128 + n]);
}

// ---------------------------------------------------------------------------
// bf16 MFMA GEMM: out = act( [A | Bm] @ W^T-layout + bias )
// W is pre-transposed bf16 [128 n][KTOT k].  A,Bm bf16 [NN][128].
// 128x128 tile/block, 4 waves, each wave 4x4 tiles of 16x16x32 MFMA.
// LDS tiles padded to stride 40 (80 B) -> uniform bank load.
// OUTBF: write bf16, else fp32.
// ---------------------------------------------------------------------------
template <bool RELU, bool TWO, bool OUTBF>
__global__ __launch_bounds__(256, 3) void gemm_bf16(
    const ushort_t* __restrict__ A, const ushort_t* __restrict__ Bm,
    const ushort_t* __restrict__ W, const float* __restrict__ bias,
    void* __restrict__ outv)
{
    __shared__ ushort_t At[128 * 40];   // 10 KB
    __shared__ ushort_t Wt[128 * 40];   // 10 KB

    const int tid  = threadIdx.x;
    const int lane = tid & 63;
    const int wav  = tid >> 6;
    const int row0 = blockIdx.x * 128;
    const int m0   = (wav & 1) * 64;
    const int n0   = (wav >> 1) * 64;
    const int KTOT = TWO ? 256 : 128;
    const int NCH  = TWO ? 8 : 4;

    f32x4 acc[4][4];
#pragma unroll
    for (int i = 0; i < 4; ++i)
#pragma unroll
        for (int j = 0; j < 4; ++j) acc[i][j] = (f32x4){0.f, 0.f, 0.f, 0.f};

    const int cl = lane & 15;      // col-in-tile / row-in-tile
    const int q  = lane >> 4;      // k-quad

#pragma unroll 1
    for (int ch = 0; ch < NCH; ++ch) {
        const ushort_t* __restrict__ sp = (TWO && ch >= 4) ? Bm : A;
        const int kA = (ch & 3) * 32;
        const int kW = ch * 32;

        uint4 av[2], wv[2];
#pragma unroll
        for (int j = 0; j < 2; ++j) {
            int g = tid + 256 * j;            // 0..511
            int r = g >> 2;                   // 0..127
            int c = (g & 3) * 8;              // bf16 offset in 32-wide chunk
            int grow = row0 + r;
            if (grow >= NN) grow = NN - 1;    // clamp; masked at write
            av[j] = *(const uint4*)(sp + (size_t)grow * DD + kA + c);
            wv[j] = *(const uint4*)(W + (size_t)r * KTOT + kW + c);
        }
        if (ch) __syncthreads();              // prev compute done before overwrite
#pragma unroll
        for (int j = 0; j < 2; ++j) {
            int g = tid + 256 * j;
            int r = g >> 2;
            int c = (g & 3) * 8;
            *(uint4*)(&At[r * 40 + c]) = av[j];
            *(uint4*)(&Wt[r * 40 + c]) = wv[j];
        }
        __syncthreads();

        bf16x8 af[4], bfr[4];
#pragma unroll
        for (int i = 0; i < 4; ++i)
            af[i] = *(const bf16x8*)(&At[(m0 + i * 16 + cl) * 40 + q * 8]);
#pragma unroll
        for (int j = 0; j < 4; ++j)
            bfr[j] = *(const bf16x8*)(&Wt[(n0 + j * 16 + cl) * 40 + q * 8]);
#pragma unroll
        for (int i = 0; i < 4; ++i)
#pragma unroll
            for (int j = 0; j < 4; ++j)
                acc[i][j] = __builtin_amdgcn_mfma_f32_16x16x32_bf16(
                    af[i], bfr[j], acc[i][j], 0, 0, 0);
    }

    // Epilogue: C/D layout col=lane&15, row=(lane>>4)*4+reg  [m89/m91]
#pragma unroll
    for (int j = 0; j < 4; ++j) {
        int col = n0 + j * 16 + cl;
        float bv = bias[col];
#pragma unroll
        for (int i = 0; i < 4; ++i) {
            int rbase = row0 + m0 + i * 16 + 4 * q;
#pragma unroll
            for (int reg = 0; reg < 4; ++reg) {
                int row = rbase + reg;
                if (row < NN) {
                    float v = acc[i][j][reg] + bv;
                    if constexpr (RELU) v = fmaxf(v, 0.f);
                    if constexpr (OUTBF)
                        ((ushort_t*)outv)[(size_t)row * DD + col] = f2bf(v);
                    else
                        ((float*)outv)[(size_t)row * DD + col] = v;
                }
            }
        }
    }
}

// ---------------------------------------------------------------------------
// CSR build
// ---------------------------------------------------------------------------
__global__ __launch_bounds__(256) void count_kernel(
    const int* __restrict__ dst, int* __restrict__ counts, int E)
{
    int e = blockIdx.x * 256 + threadIdx.x;
    if (e < E) atomicAdd(&counts[dst[e]], 1);
}

__global__ __launch_bounds__(256) void scan1(
    const int* __restrict__ counts, int* __restrict__ offs,
    int* __restrict__ partials, int n)
{
    __shared__ int lds[256];
    const int tid  = threadIdx.x;
    const int base = blockIdx.x * 1024 + tid * 4;
    int v[4], s = 0;
#pragma unroll
    for (int i = 0; i < 4; ++i) {
        v[i] = (base + i < n) ? counts[base + i] : 0;
        s += v[i];
    }
    lds[tid] = s;
    __syncthreads();
    for (int off = 1; off < 256; off <<= 1) {
        int t = 0;
        if (tid >= off) t = lds[tid - off];
        __syncthreads();
        if (tid >= off) lds[tid] += t;
        __syncthreads();
    }
    int run = lds[tid] - s;
#pragma unroll
    for (int i = 0; i < 4; ++i) {
        if (base + i < n) offs[base + i] = run;
        run += v[i];
    }
    if (tid == 255) partials[blockIdx.x] = lds[255];
}

__global__ __launch_bounds__(128) void scan2(int* __restrict__ partials, int nb)
{
    __shared__ int lds[128];
    const int tid = threadIdx.x;
    int v = (tid < nb) ? partials[tid] : 0;
    lds[tid] = v;
    __syncthreads();
    for (int off = 1; off < 128; off <<= 1) {
        int t = 0;
        if (tid >= off) t = lds[tid - off];
        __syncthreads();
        if (tid >= off) lds[tid] += t;
        __syncthreads();
    }
    if (tid < nb) partials[tid] = lds[tid] - v;
}

__global__ __launch_bounds__(256) void scan3(
    int* __restrict__ offs, int* __restrict__ cursor,
    const int* __restrict__ partials, int n)
{
    int i = blockIdx.x * 256 + threadIdx.x;
    if (i < n) {
        int o = offs[i] + partials[i >> 10];
        offs[i]   = o;
        cursor[i] = o;
    }
}

__global__ __launch_bounds__(256) void fill_kernel(
    const int* __restrict__ src, const int* __restrict__ dst,
    int* __restrict__ cursor, int* __restrict__ csr, int E)
{
    int e = blockIdx.x * 256 + threadIdx.x;
    if (e < E) {
        int pos = atomicAdd(&cursor[dst[e]], 1);
        csr[pos] = src[e];
    }
}

// ---------------------------------------------------------------------------
// CSR mean-aggregate over bf16 h: mean[n] = sum(h[src])/max(deg,1), bf16 out.
// 32 lanes/node, 4 bf16 (8 B) per lane, fp32 accumulation.
// ---------------------------------------------------------------------------
__global__ __launch_bounds__(256) void aggregate_bf16(
    const ushort_t* __restrict__ h, const int* __restrict__ csr,
    const int* __restrict__ offs, const int* __restrict__ counts,
    ushort_t* __restrict__ mean, int nn)
{
    int gid  = blockIdx.x * 256 + threadIdx.x;
    int node = gid >> 5;
    if (node >= nn) return;
    int lane  = gid & 31;
    int start = offs[node];
    int cnt   = counts[node];

    float a0 = 0.f, a1 = 0.f, a2 = 0.f, a3 = 0.f;
    int j = 0;
    for (; j + 4 <= cnt; j += 4) {
        int s0 = csr[start + j + 0];
        int s1 = csr[start + j + 1];
        int s2 = csr[start + j + 2];
        int s3 = csr[start + j + 3];
        uint2 v0 = *(const uint2*)(h + (size_t)s0 * DD + lane * 4);
        uint2 v1 = *(const uint2*)(h + (size_t)s1 * DD + lane * 4);
        uint2 v2 = *(const uint2*)(h + (size_t)s2 * DD + lane * 4);
        uint2 v3 = *(const uint2*)(h + (size_t)s3 * DD + lane * 4);
        a0 += bflo(v0.x) + bflo(v1.x) + bflo(v2.x) + bflo(v3.x);
        a1 += bfhi(v0.x) + bfhi(v1.x) + bfhi(v2.x) + bfhi(v3.x);
        a2 += bflo(v0.y) + bflo(v1.y) + bflo(v2.y) + bflo(v3.y);
        a3 += bfhi(v0.y) + bfhi(v1.y) + bfhi(v2.y) + bfhi(v3.y);
    }
    for (; j < cnt; ++j) {
        int s = csr[start + j];
        uint2 v = *(const uint2*)(h + (size_t)s * DD + lane * 4);
        a0 += bflo(v.x); a1 += bfhi(v.x);
        a2 += bflo(v.y); a3 += bfhi(v.y);
    }
    float rinv = 1.0f / (float)(cnt > 1 ? cnt : 1);
    uint2 o;
    o.x = pack2bf(a0 * rinv, a1 * rinv);
    o.y = pack2bf(a2 * rinv, a3 * rinv);
    *(uint2*)(mean + (size_t)node * DD + lane * 4) = o;
}

// ---------------------------------------------------------------------------
// Edge scoring on fp32 h3: out[e] = dot(h[src], h[dst]).  32 lanes/edge.
// ---------------------------------------------------------------------------
__global__ __launch_bounds__(256) void score_kernel(
    const float* __restrict__ h, const int* __restrict__ src,
    const int* __restrict__ dst, float* __restrict__ out, int E)
{
    int gid = blockIdx.x * 256 + threadIdx.x;
    int e = gid >> 5;
    if (e >= E) return;
    int lane = gid & 31;
    const float4 a = *(const float4*)(h + (size_t)src[e] * DD + lane * 4);
    const float4 b = *(const float4*)(h + (size_t)dst[e] * DD + lane * 4);
    float s = a.x * b.x + a.y * b.y + a.z * b.z + a.w * b.w;
#pragma unroll
    for (int off = 16; off; off >>= 1) s += __shfl_down(s, off, 32);
    if (lane == 0) out[e] = s;
}

// ---------------------------------------------------------------------------

static void build_csr_and_aggregate(const ushort_t* h, const int* esrc,
                                    const int* edst, int E, int* ints,
                                    ushort_t* mean, hipStream_t stream)
{
    int* counts   = ints;                    // [NN]
    int* offs     = ints + NN;               // [NN]
    int* cursor   = ints + 2 * NN;           // [NN]
    int* partials = ints + 3 * NN;           // [128]
    int* csr      = ints + 3 * NN + 128;     // [E]

    const int NB = (NN + 1023) / 1024;       // 98

    hipMemsetAsync(counts, 0, NN * sizeof(int), stream);
    count_kernel<<<(E + 255) / 256, 256, 0, stream>>>(edst, counts, E);
    scan1<<<NB, 256, 0, stream>>>(counts, offs, partials, NN);
    scan2<<<1, 128, 0, stream>>>(partials, NB);
    scan3<<<(NN + 255) / 256, 256, 0, stream>>>(offs, cursor, partials, NN);
    fill_kernel<<<(E + 255) / 256, 256, 0, stream>>>(esrc, edst, cursor, csr, E);
    aggregate_bf16<<<(NN * 32 + 255) / 256, 256, 0, stream>>>(
        h, csr, offs, counts, mean, NN);
}

extern "C" void kernel_launch(void* const* d_in, const int* in_sizes, int n_in,
                              void* d_out, int out_size, void* d_ws, size_t ws_size,
                              hipStream_t stream)
{
    const float* feat    = (const float*)d_in[0];
    const int*   e0s     = (const int*)d_in[1];
    const int*   e0d     = (const int*)d_in[2];
    const int*   e1s     = (const int*)d_in[3];
    const int*   e1d     = (const int*)d_in[4];
    const int*   ps      = (const int*)d_in[5];
    const int*   pd      = (const int*)d_in[6];
    const int*   ns      = (const int*)d_in[7];
    const int*   nd      = (const int*)d_in[8];
    const float* w_proj  = (const float*)d_in[9];
    const float* b_proj  = (const float*)d_in[10];
    const float* w_self1 = (const float*)d_in[11];
    const float* w_neigh1= (const float*)d_in[12];
    const float* b1      = (const float*)d_in[13];
    const float* w_self2 = (const float*)d_in[14];
    const float* w_neigh2= (const float*)d_in[15];
    const float* b2      = (const float*)d_in[16];

    float* out = (float*)d_out;

    const size_t NF  = (size_t)NN * DD;      // 12.8 M elems
    char* base = (char*)d_ws;

    // Region 0 (NF fp32 = 51.2 MB): featb + h1 early; h3 (fp32) late.
    float*    h3    = (float*)base;
    ushort_t* featb = (ushort_t*)base;                 // NF bf16
    ushort_t* h1    = (ushort_t*)(base + NF * 2);      // NF bf16
    ushort_t* mean  = (ushort_t*)(base + NF * 4);      // NF bf16
    ushort_t* h2    = (ushort_t*)(base + NF * 6);      // NF bf16
    int*      ints  = (int*)(base + NF * 8);           // 3*NN+128+1.6M ints
    ushort_t* wts   = (ushort_t*)(base + NF * 8 + (size_t)(3 * NN + 128 + 1600000) * 4);
    ushort_t* wtp = wts;                // [128][128]
    ushort_t* wt1 = wts + 128 * 128;    // [128][256]
    ushort_t* wt2 = wt1 + 128 * 256;    // [128][256]

    const int E0 = in_sizes[1];
    const int E1 = in_sizes[3];
    const int EP = in_sizes[5];
    const int EN = in_sizes[7];

    const int GB = (NN + 127) / 128;    // 782

    // ---- Prep: feat -> bf16; weights -> transposed bf16
    convert_feat<<<(int)(NF / 8 / 256), 256, 0, stream>>>(feat, featb);
    prep_w<<<64, 256, 0, stream>>>(w_proj,   wtp, 128, 0);
    prep_w<<<64, 256, 0, stream>>>(w_self1,  wt1, 256, 0);
    prep_w<<<64, 256, 0, stream>>>(w_neigh1, wt1, 256, 128);
    prep_w<<<64, 256, 0, stream>>>(w_self2,  wt2, 256, 0);
    prep_w<<<64, 256, 0, stream>>>(w_neigh2, wt2, 256, 128);

    // ---- Layer 0: h1 = relu(feat @ w_proj + b_proj)
    gemm_bf16<true, false, true><<<GB, 256, 0, stream>>>(
        featb, nullptr, wtp, b_proj, h1);

    // ---- Layer 1: mean(edge0, h1) -> mean; h2 = relu([h1|mean]@[Ws1;Wn1]+b1)
    build_csr_and_aggregate(h1, e0s, e0d, E0, ints, mean, stream);
    gemm_bf16<true, true, true><<<GB, 256, 0, stream>>>(
        h1, mean, wt1, b1, h2);

    // ---- Layer 2: mean(edge1, h2) -> mean; h3 = [h2|mean]@[Ws2;Wn2]+b2 (fp32)
    build_csr_and_aggregate(h2, e1s, e1d, E1, ints, mean, stream);
    gemm_bf16<false, true, false><<<GB, 256, 0, stream>>>(
        h2, mean, wt2, b2, h3);

    // ---- Scoring on fp32 h3
    score_kernel<<<(EP * 32 + 255) / 256, 256, 0, stream>>>(h3, ps, pd, out, EP);
    score_kernel<<<(EN * 32 + 255) / 256, 256, 0, stream>>>(h3, ns, nd, out + EP, EN);
}

// Round 5
// 590.640 us; speedup vs baseline: 10.3671x; 1.4437x over previous
//
#include <hip/hip_runtime.h>
#include <hip/hip_bf16.h>

#define NN 100000
#define DD 128

// Bucketed CSR build
#define NPB_SHIFT 9
#define NPB 512                    // nodes per bucket
#define NB 196                     // ceil(100000/512)
#define CAPB 12288                 // pairs per bucket (mean 8192, ~45 sigma slack)

typedef unsigned short ushort_t;
typedef unsigned int uint_t;
typedef __attribute__((ext_vector_type(8))) short bf16x8;
typedef __attribute__((ext_vector_type(4))) float f32x4;

__device__ __forceinline__ ushort_t f2bf(float f) {
    uint_t u = __builtin_bit_cast(uint_t, f);
    u += 0x7FFFu + ((u >> 16) & 1u);          // RNE
    return (ushort_t)(u >> 16);
}
__device__ __forceinline__ uint_t pack2bf(float a, float b) {
    return (uint_t)f2bf(a) | ((uint_t)f2bf(b) << 16);
}
__device__ __forceinline__ float bflo(uint_t v) {
    return __builtin_bit_cast(float, v << 16);
}
__device__ __forceinline__ float bfhi(uint_t v) {
    return __builtin_bit_cast(float, v & 0xFFFF0000u);
}

// ---------------------------------------------------------------------------
// feat fp32 -> bf16, 8 elems/thread
// ---------------------------------------------------------------------------
__global__ __launch_bounds__(256) void convert_feat(
    const float* __restrict__ src, ushort_t* __restrict__ dst)
{
    size_t t = (size_t)blockIdx.x * 256 + threadIdx.x;
    size_t base = t * 8;
    float4 a = *(const float4*)(src + base);
    float4 b = *(const float4*)(src + base + 4);
    uint4 o;
    o.x = pack2bf(a.x, a.y); o.y = pack2bf(a.z, a.w);
    o.z = pack2bf(b.x, b.y); o.w = pack2bf(b.z, b.w);
    *(uint4*)(dst + base) = o;
}

// ---------------------------------------------------------------------------
// weight prep: dst[n*Ktot + koff + k] = bf16(src[k*128 + n])
// ---------------------------------------------------------------------------
__global__ __launch_bounds__(256) void prep_w(
    const float* __restrict__ src, ushort_t* __restrict__ dst,
    int Ktot, int koff)
{
    int t = blockIdx.x * 256 + threadIdx.x;
    if (t >= 128 * 128) return;
    int n = t >> 7, k = t & 127;
    dst[(size_t)n * Ktot + koff + k] = f2bf(src[(size_t)k * 128 + n]);
}

// ---------------------------------------------------------------------------
// bf16 MFMA GEMM: out = act( [A | Bm] @ W + bias ), W pre-transposed [n][k].
// 128x128 tile/block, 4 waves x (4x4) 16x16x32 MFMA tiles, BK=32.
// Epilogue stages the output tile in LDS (32KB) -> coalesced 16B row writes.
// ---------------------------------------------------------------------------
template <bool RELU, bool TWO, bool OUTBF>
__global__ __launch_bounds__(256, 3) void gemm_bf16(
    const ushort_t* __restrict__ A, const ushort_t* __restrict__ Bm,
    const ushort_t* __restrict__ W, const float* __restrict__ bias,
    void* __restrict__ outv)
{
    __shared__ ushort_t At[128 * 40];   // 10 KB
    __shared__ ushort_t Wt[128 * 40];   // 10 KB
    __shared__ char     OB[32768];      // 32 KB output staging

    const int tid  = threadIdx.x;
    const int lane = tid & 63;
    const int wav  = tid >> 6;
    const int row0 = blockIdx.x * 128;
    const int m0   = (wav & 1) * 64;
    const int n0   = (wav >> 1) * 64;
    const int KTOT = TWO ? 256 : 128;
    const int NCH  = TWO ? 8 : 4;

    f32x4 acc[4][4];
#pragma unroll
    for (int i = 0; i < 4; ++i)
#pragma unroll
        for (int j = 0; j < 4; ++j) acc[i][j] = (f32x4){0.f, 0.f, 0.f, 0.f};

    const int cl = lane & 15;
    const int q  = lane >> 4;

#pragma unroll 1
    for (int ch = 0; ch < NCH; ++ch) {
        const ushort_t* __restrict__ sp = (TWO && ch >= 4) ? Bm : A;
        const int kA = (ch & 3) * 32;
        const int kW = ch * 32;

        uint4 av[2], wv[2];
#pragma unroll
        for (int j = 0; j < 2; ++j) {
            int g = tid + 256 * j;
            int r = g >> 2;
            int c = (g & 3) * 8;
            int grow = row0 + r;
            if (grow >= NN) grow = NN - 1;
            av[j] = *(const uint4*)(sp + (size_t)grow * DD + kA + c);
            wv[j] = *(const uint4*)(W + (size_t)r * KTOT + kW + c);
        }
        if (ch) __syncthreads();
#pragma unroll
        for (int j = 0; j < 2; ++j) {
            int g = tid + 256 * j;
            int r = g >> 2;
            int c = (g & 3) * 8;
            *(uint4*)(&At[r * 40 + c]) = av[j];
            *(uint4*)(&Wt[r * 40 + c]) = wv[j];
        }
        __syncthreads();

        bf16x8 af[4], bfr[4];
#pragma unroll
        for (int i = 0; i < 4; ++i)
            af[i] = *(const bf16x8*)(&At[(m0 + i * 16 + cl) * 40 + q * 8]);
#pragma unroll
        for (int j = 0; j < 4; ++j)
            bfr[j] = *(const bf16x8*)(&Wt[(n0 + j * 16 + cl) * 40 + q * 8]);
#pragma unroll
        for (int i = 0; i < 4; ++i)
#pragma unroll
            for (int j = 0; j < 4; ++j)
                acc[i][j] = __builtin_amdgcn_mfma_f32_16x16x32_bf16(
                    af[i], bfr[j], acc[i][j], 0, 0, 0);
    }

    // Epilogue. C/D layout: col=lane&15, row=(lane>>4)*4+reg  [m89/m91]
    if constexpr (OUTBF) {
        ushort_t* Ot = (ushort_t*)OB;            // [128][128]
#pragma unroll
        for (int j = 0; j < 4; ++j) {
            int c = n0 + j * 16 + cl;
            float bv = bias[c];
#pragma unroll
            for (int i = 0; i < 4; ++i) {
#pragma unroll
                for (int reg = 0; reg < 4; ++reg) {
                    int r = m0 + i * 16 + 4 * q + reg;
                    float v = acc[i][j][reg] + bv;
                    if constexpr (RELU) v = fmaxf(v, 0.f);
                    Ot[r * 128 + c] = f2bf(v);
                }
            }
        }
        __syncthreads();
        int rows = NN - row0; if (rows > 128) rows = 128;
        for (int t = tid; t < rows * 16; t += 256) {
            int r = t >> 4, c8 = (t & 15) * 8;
            *(uint4*)((ushort_t*)outv + (size_t)(row0 + r) * DD + c8) =
                *(const uint4*)(&Ot[r * 128 + c8]);
        }
    } else {
        float* Of = (float*)OB;                  // [64][128]
#pragma unroll 1
        for (int p = 0; p < 2; ++p) {
            if (m0 == p * 64) {
#pragma unroll
                for (int j = 0; j < 4; ++j) {
                    int c = n0 + j * 16 + cl;
                    float bv = bias[c];
#pragma unroll
                    for (int i = 0; i < 4; ++i) {
#pragma unroll
                        for (int reg = 0; reg < 4; ++reg) {
                            int r = i * 16 + 4 * q + reg;
                            float v = acc[i][j][reg] + bv;
                            if constexpr (RELU) v = fmaxf(v, 0.f);
                            Of[r * 128 + c] = v;
                        }
                    }
                }
            }
            __syncthreads();
            int rbase = row0 + p * 64;
            int rows = NN - rbase;
            if (rows < 0) rows = 0;
            if (rows > 64) rows = 64;
            for (int t = tid; t < rows * 32; t += 256) {
                int r = t >> 5, c4 = (t & 31) * 4;
                *(float4*)((float*)outv + (size_t)(rbase + r) * DD + c4) =
                    *(const float4*)(&Of[r * 128 + c4]);
            }
            __syncthreads();
        }
    }
}

// ---------------------------------------------------------------------------
// Bucketed CSR build.
// Phase A: partition edges into NB buckets of (src,dst) pairs.
// ---------------------------------------------------------------------------
__global__ __launch_bounds__(256) void partA(
    const int* __restrict__ src, const int* __restrict__ dst, int E,
    int* __restrict__ bcnt, uint2* __restrict__ pairs)
{
    __shared__ int hist[NB];
    __shared__ int base[NB];
    const int tid = threadIdx.x;
    const int chunk = (E + gridDim.x - 1) / gridDim.x;
    const int e0 = blockIdx.x * chunk;
    int e1 = e0 + chunk; if (e1 > E) e1 = E;

    for (int b = tid; b < NB; b += 256) hist[b] = 0;
    __syncthreads();
    for (int e = e0 + tid; e < e1; e += 256)
        atomicAdd(&hist[dst[e] >> NPB_SHIFT], 1);
    __syncthreads();
    for (int b = tid; b < NB; b += 256) {
        base[b] = atomicAdd(&bcnt[b], hist[b]);
        hist[b] = 0;
    }
    __syncthreads();
    for (int e = e0 + tid; e < e1; e += 256) {
        int d = dst[e];
        int b = d >> NPB_SHIFT;
        int off = atomicAdd(&hist[b], 1);
        int p = base[b] + off;
        if (p < CAPB) pairs[(size_t)b * CAPB + p] = make_uint2((uint_t)src[e], (uint_t)d);
    }
}

// Exclusive scan over NB bucket totals (single block); clamps totals to CAPB.
__global__ __launch_bounds__(256) void bscan(
    int* __restrict__ bcnt, int* __restrict__ bbase)
{
    __shared__ int lds[256];
    const int tid = threadIdx.x;
    int v = 0;
    if (tid < NB) { v = bcnt[tid]; if (v > CAPB) v = CAPB; }
    lds[tid] = v;
    __syncthreads();
    for (int off = 1; off < 256; off <<= 1) {
        int t = 0;
        if (tid >= off) t = lds[tid - off];
        __syncthreads();
        if (tid >= off) lds[tid] += t;
        __syncthreads();
    }
    if (tid < NB) { bbase[tid] = lds[tid] - v; bcnt[tid] = v; }
}

// Phase B: one block per bucket — local count/scan/place in LDS, then stream
// the finished csr segment out coalesced. Produces counts[] and offs[] too.
__global__ __launch_bounds__(256) void partB(
    const uint2* __restrict__ pairs, const int* __restrict__ bcnt,
    const int* __restrict__ bbase, int* __restrict__ counts,
    int* __restrict__ offs, int* __restrict__ csr)
{
    __shared__ int cnt[NPB];
    __shared__ int loff[NPB];
    __shared__ int ssc[256];
    __shared__ int image[CAPB];

    const int tid = threadIdx.x;
    const int b   = blockIdx.x;
    const int n0  = b << NPB_SHIFT;
    int nb = NN - n0; if (nb > NPB) nb = NPB;
    const int tot   = bcnt[b];
    const int gbase = bbase[b];
    const uint2* pb = pairs + (size_t)b * CAPB;

    for (int n = tid; n < NPB; n += 256) cnt[n] = 0;
    __syncthreads();
    for (int i = tid; i < tot; i += 256)
        atomicAdd(&cnt[pb[i].y - n0], 1);
    __syncthreads();

    // exclusive scan of cnt[0..511] with 256 threads
    int a0 = cnt[2 * tid], a1 = cnt[2 * tid + 1];
    int s = a0 + a1;
    ssc[tid] = s;
    __syncthreads();
    for (int off = 1; off < 256; off <<= 1) {
        int t = 0;
        if (tid >= off) t = ssc[tid - off];
        __syncthreads();
        if (tid >= off) ssc[tid] += t;
        __syncthreads();
    }
    int pre = ssc[tid] - s;
    loff[2 * tid]     = pre;
    loff[2 * tid + 1] = pre + a0;
    __syncthreads();

    for (int n = tid; n < nb; n += 256) {
        counts[n0 + n] = cnt[n];
        offs[n0 + n]   = gbase + loff[n];
    }
    for (int n = tid; n < NPB; n += 256) cnt[n] = 0;   // reuse as cursor
    __syncthreads();

    for (int i = tid; i < tot; i += 256) {
        uint2 p = pb[i];
        int ln  = p.y - n0;
        int pos = loff[ln] + atomicAdd(&cnt[ln], 1);
        image[pos] = (int)p.x;
    }
    __syncthreads();
    for (int i = tid; i < tot; i += 256) csr[gbase + i] = image[i];
}

// ---------------------------------------------------------------------------
// CSR mean-aggregate over bf16 h: mean[n] = sum(h[src])/max(deg,1), bf16 out.
// ---------------------------------------------------------------------------
__global__ __launch_bounds__(256) void aggregate_bf16(
    const ushort_t* __restrict__ h, const int* __restrict__ csr,
    const int* __restrict__ offs, const int* __restrict__ counts,
    ushort_t* __restrict__ mean, int nn)
{
    int gid  = blockIdx.x * 256 + threadIdx.x;
    int node = gid >> 5;
    if (node >= nn) return;
    int lane  = gid & 31;
    int start = offs[node];
    int cnt   = counts[node];

    float a0 = 0.f, a1 = 0.f, a2 = 0.f, a3 = 0.f;
    int j = 0;
    for (; j + 4 <= cnt; j += 4) {
        int s0 = csr[start + j + 0];
        int s1 = csr[start + j + 1];
        int s2 = csr[start + j + 2];
        int s3 = csr[start + j + 3];
        uint2 v0 = *(const uint2*)(h + (size_t)s0 * DD + lane * 4);
        uint2 v1 = *(const uint2*)(h + (size_t)s1 * DD + lane * 4);
        uint2 v2 = *(const uint2*)(h + (size_t)s2 * DD + lane * 4);
        uint2 v3 = *(const uint2*)(h + (size_t)s3 * DD + lane * 4);
        a0 += bflo(v0.x) + bflo(v1.x) + bflo(v2.x) + bflo(v3.x);
        a1 += bfhi(v0.x) + bfhi(v1.x) + bfhi(v2.x) + bfhi(v3.x);
        a2 += bflo(v0.y) + bflo(v1.y) + bflo(v2.y) + bflo(v3.y);
        a3 += bfhi(v0.y) + bfhi(v1.y) + bfhi(v2.y) + bfhi(v3.y);
    }
    for (; j < cnt; ++j) {
        int s = csr[start + j];
        uint2 v = *(const uint2*)(h + (size_t)s * DD + lane * 4);
        a0 += bflo(v.x); a1 += bfhi(v.x);
        a2 += bflo(v.y); a3 += bfhi(v.y);
    }
    float rinv = 1.0f / (float)(cnt > 1 ? cnt : 1);
    uint2 o;
    o.x = pack2bf(a0 * rinv, a1 * rinv);
    o.y = pack2bf(a2 * rinv, a3 * rinv);
    *(uint2*)(mean + (size_t)node * DD + lane * 4) = o;
}

// ---------------------------------------------------------------------------
// Edge scoring on fp32 h3
// ---------------------------------------------------------------------------
__global__ __launch_bounds__(256) void score_kernel(
    const float* __restrict__ h, const int* __restrict__ src,
    const int* __restrict__ dst, float* __restrict__ out, int E)
{
    int gid = blockIdx.x * 256 + threadIdx.x;
    int e = gid >> 5;
    if (e >= E) return;
    int lane = gid & 31;
    const float4 a = *(const float4*)(h + (size_t)src[e] * DD + lane * 4);
    const float4 b = *(const float4*)(h + (size_t)dst[e] * DD + lane * 4);
    float s = a.x * b.x + a.y * b.y + a.z * b.z + a.w * b.w;
#pragma unroll
    for (int off = 16; off; off >>= 1) s += __shfl_down(s, off, 32);
    if (lane == 0) out[e] = s;
}

// ---------------------------------------------------------------------------

static void build_csr_and_aggregate(const ushort_t* h, const int* esrc,
                                    const int* edst, int E,
                                    uint2* pairs, int* bcnt, int* bbase,
                                    int* counts, int* offs, int* csr,
                                    ushort_t* mean, hipStream_t stream)
{
    hipMemsetAsync(bcnt, 0, NB * sizeof(int), stream);
    partA<<<NB, 256, 0, stream>>>(esrc, edst, E, bcnt, pairs);
    bscan<<<1, 256, 0, stream>>>(bcnt, bbase);
    partB<<<NB, 256, 0, stream>>>(pairs, bcnt, bbase, counts, offs, csr);
    aggregate_bf16<<<(NN * 32 + 255) / 256, 256, 0, stream>>>(
        h, csr, offs, counts, mean, NN);
}

extern "C" void kernel_launch(void* const* d_in, const int* in_sizes, int n_in,
                              void* d_out, int out_size, void* d_ws, size_t ws_size,
                              hipStream_t stream)
{
    const float* feat    = (const float*)d_in[0];
    const int*   e0s     = (const int*)d_in[1];
    const int*   e0d     = (const int*)d_in[2];
    const int*   e1s     = (const int*)d_in[3];
    const int*   e1d     = (const int*)d_in[4];
    const int*   ps      = (const int*)d_in[5];
    const int*   pd      = (const int*)d_in[6];
    const int*   ns      = (const int*)d_in[7];
    const int*   nd      = (const int*)d_in[8];
    const float* w_proj  = (const float*)d_in[9];
    const float* b_proj  = (const float*)d_in[10];
    const float* w_self1 = (const float*)d_in[11];
    const float* w_neigh1= (const float*)d_in[12];
    const float* b1      = (const float*)d_in[13];
    const float* w_self2 = (const float*)d_in[14];
    const float* w_neigh2= (const float*)d_in[15];
    const float* b2      = (const float*)d_in[16];

    float* out = (float*)d_out;

    const size_t NF = (size_t)NN * DD;
    char* base = (char*)d_ws;

    // [0, NF*4): featb (bf16, dies after layer-0 gemm) then h3 (fp32);
    //            h1 lives in the upper half [NF*2, NF*4).
    float*    h3    = (float*)base;
    ushort_t* featb = (ushort_t*)base;
    ushort_t* h1    = (ushort_t*)(base + NF * 2);
    ushort_t* mean  = (ushort_t*)(base + NF * 4);
    ushort_t* h2    = (ushort_t*)(base + NF * 6);

    uint2* pairs = (uint2*)(base + NF * 8);                  // NB*CAPB*8 B
    int*   ints  = (int*)((char*)pairs + (size_t)NB * CAPB * 8);
    int* counts = ints;                  // [NN]
    int* offs   = ints + NN;             // [NN]
    int* csr    = ints + 2 * NN;         // [1.6M]
    int* bcnt   = ints + 2 * NN + 1600000;
    int* bbase  = bcnt + 256;
    ushort_t* wts = (ushort_t*)(bbase + 256);
    ushort_t* wtp = wts;                 // [128][128]
    ushort_t* wt1 = wts + 128 * 128;     // [128][256]
    ushort_t* wt2 = wt1 + 128 * 256;     // [128][256]

    const int E0 = in_sizes[1];
    const int E1 = in_sizes[3];
    const int EP = in_sizes[5];
    const int EN = in_sizes[7];

    const int GB = (NN + 127) / 128;     // 782

    // ---- Prep
    convert_feat<<<(int)(NF / 8 / 256), 256, 0, stream>>>(feat, featb);
    prep_w<<<64, 256, 0, stream>>>(w_proj,   wtp, 128, 0);
    prep_w<<<64, 256, 0, stream>>>(w_self1,  wt1, 256, 0);
    prep_w<<<64, 256, 0, stream>>>(w_neigh1, wt1, 256, 128);
    prep_w<<<64, 256, 0, stream>>>(w_self2,  wt2, 256, 0);
    prep_w<<<64, 256, 0, stream>>>(w_neigh2, wt2, 256, 128);

    // ---- Layer 0: h1 = relu(feat @ w_proj + b_proj)
    gemm_bf16<true, false, true><<<GB, 256, 0, stream>>>(
        featb, nullptr, wtp, b_proj, h1);

    // ---- Layer 1
    build_csr_and_aggregate(h1, e0s, e0d, E0, pairs, bcnt, bbase,
                            counts, offs, csr, mean, stream);
    gemm_bf16<true, true, true><<<GB, 256, 0, stream>>>(
        h1, mean, wt1, b1, h2);

    // ---- Layer 2
    build_csr_and_aggregate(h2, e1s, e1d, E1, pairs, bcnt, bbase,
                            counts, offs, csr, mean, stream);
    gemm_bf16<false, true, false><<<GB, 256, 0, stream>>>(
        h2, mean, wt2, b2, h3);

    // ---- Scoring on fp32 h3
    score_kernel<<<(EP * 32 + 255) / 256, 256, 0, stream>>>(h3, ps, pd, out, EP);
    score_kernel<<<(EN * 32 + 255) / 256, 256, 0, stream>>>(h3, ns, nd, out + EP, EN);
}

// Round 6
// 561.220 us; speedup vs baseline: 10.9105x; 1.0524x over previous
//
#include <hip/hip_runtime.h>
#include <hip/hip_bf16.h>

#define NN 100000
#define DD 128

// Bucketed CSR build
#define NPB_SHIFT 9
#define NPB 512                    // nodes per bucket
#define NB 196                     // ceil(100000/512)
#define CAPB 12288                 // pairs per bucket (mean 8192, huge slack)

typedef unsigned short ushort_t;
typedef unsigned int uint_t;
typedef __attribute__((ext_vector_type(8))) short bf16x8;
typedef __attribute__((ext_vector_type(4))) float f32x4;

__device__ __forceinline__ ushort_t f2bf(float f) {
    uint_t u = __builtin_bit_cast(uint_t, f);
    u += 0x7FFFu + ((u >> 16) & 1u);          // RNE
    return (ushort_t)(u >> 16);
}
__device__ __forceinline__ uint_t pack2bf(float a, float b) {
    return (uint_t)f2bf(a) | ((uint_t)f2bf(b) << 16);
}
__device__ __forceinline__ float bflo(uint_t v) {
    return __builtin_bit_cast(float, v << 16);
}
__device__ __forceinline__ float bfhi(uint_t v) {
    return __builtin_bit_cast(float, v & 0xFFFF0000u);
}

// ---------------------------------------------------------------------------
// feat fp32 -> bf16, 8 elems/thread
// ---------------------------------------------------------------------------
__global__ __launch_bounds__(256) void convert_feat(
    const float* __restrict__ src, ushort_t* __restrict__ dst)
{
    size_t t = (size_t)blockIdx.x * 256 + threadIdx.x;
    size_t base = t * 8;
    float4 a = *(const float4*)(src + base);
    float4 b = *(const float4*)(src + base + 4);
    uint4 o;
    o.x = pack2bf(a.x, a.y); o.y = pack2bf(a.z, a.w);
    o.z = pack2bf(b.x, b.y); o.w = pack2bf(b.z, b.w);
    *(uint4*)(dst + base) = o;
}

// ---------------------------------------------------------------------------
// weight prep: dst[n*Ktot + koff + k] = bf16(src[k*128 + n])
// ---------------------------------------------------------------------------
__global__ __launch_bounds__(256) void prep_w(
    const float* __restrict__ src, ushort_t* __restrict__ dst,
    int Ktot, int koff)
{
    int t = blockIdx.x * 256 + threadIdx.x;
    if (t >= 128 * 128) return;
    int n = t >> 7, k = t & 127;
    dst[(size_t)n * Ktot + koff + k] = f2bf(src[(size_t)k * 128 + n]);
}

// ---------------------------------------------------------------------------
// bf16 MFMA GEMM: out = act( [A | Bm] @ W + bias ), W pre-transposed [n][k].
// 128x128 tile/block, 4 waves x (4x4) 16x16x32 MFMA tiles, BK=32.
// Epilogue stages the bf16 output tile in LDS -> coalesced 16B row writes.
// ---------------------------------------------------------------------------
template <bool RELU, bool TWO>
__global__ __launch_bounds__(256, 3) void gemm_bf16(
    const ushort_t* __restrict__ A, const ushort_t* __restrict__ Bm,
    const ushort_t* __restrict__ W, const float* __restrict__ bias,
    ushort_t* __restrict__ outp)
{
    __shared__ ushort_t At[128 * 40];   // 10 KB
    __shared__ ushort_t Wt[128 * 40];   // 10 KB
    __shared__ ushort_t Ot[128 * 128];  // 32 KB output staging

    const int tid  = threadIdx.x;
    const int lane = tid & 63;
    const int wav  = tid >> 6;
    const int row0 = blockIdx.x * 128;
    const int m0   = (wav & 1) * 64;
    const int n0   = (wav >> 1) * 64;
    const int KTOT = TWO ? 256 : 128;
    const int NCH  = TWO ? 8 : 4;

    f32x4 acc[4][4];
#pragma unroll
    for (int i = 0; i < 4; ++i)
#pragma unroll
        for (int j = 0; j < 4; ++j) acc[i][j] = (f32x4){0.f, 0.f, 0.f, 0.f};

    const int cl = lane & 15;
    const int q  = lane >> 4;

#pragma unroll 1
    for (int ch = 0; ch < NCH; ++ch) {
        const ushort_t* __restrict__ sp = (TWO && ch >= 4) ? Bm : A;
        const int kA = (ch & 3) * 32;
        const int kW = ch * 32;

        uint4 av[2], wv[2];
#pragma unroll
        for (int j = 0; j < 2; ++j) {
            int g = tid + 256 * j;
            int r = g >> 2;
            int c = (g & 3) * 8;
            int grow = row0 + r;
            if (grow >= NN) grow = NN - 1;
            av[j] = *(const uint4*)(sp + (size_t)grow * DD + kA + c);
            wv[j] = *(const uint4*)(W + (size_t)r * KTOT + kW + c);
        }
        if (ch) __syncthreads();
#pragma unroll
        for (int j = 0; j < 2; ++j) {
            int g = tid + 256 * j;
            int r = g >> 2;
            int c = (g & 3) * 8;
            *(uint4*)(&At[r * 40 + c]) = av[j];
            *(uint4*)(&Wt[r * 40 + c]) = wv[j];
        }
        __syncthreads();

        bf16x8 af[4], bfr[4];
#pragma unroll
        for (int i = 0; i < 4; ++i)
            af[i] = *(const bf16x8*)(&At[(m0 + i * 16 + cl) * 40 + q * 8]);
#pragma unroll
        for (int j = 0; j < 4; ++j)
            bfr[j] = *(const bf16x8*)(&Wt[(n0 + j * 16 + cl) * 40 + q * 8]);
#pragma unroll
        for (int i = 0; i < 4; ++i)
#pragma unroll
            for (int j = 0; j < 4; ++j)
                acc[i][j] = __builtin_amdgcn_mfma_f32_16x16x32_bf16(
                    af[i], bfr[j], acc[i][j], 0, 0, 0);
    }

    // Epilogue. C/D layout: col=lane&15, row=(lane>>4)*4+reg  [m89/m91]
#pragma unroll
    for (int j = 0; j < 4; ++j) {
        int c = n0 + j * 16 + cl;
        float bv = bias[c];
#pragma unroll
        for (int i = 0; i < 4; ++i) {
#pragma unroll
            for (int reg = 0; reg < 4; ++reg) {
                int r = m0 + i * 16 + 4 * q + reg;
                float v = acc[i][j][reg] + bv;
                if constexpr (RELU) v = fmaxf(v, 0.f);
                Ot[r * 128 + c] = f2bf(v);
            }
        }
    }
    __syncthreads();
    int rows = NN - row0; if (rows > 128) rows = 128;
    for (int t = tid; t < rows * 16; t += 256) {
        int r = t >> 4, c8 = (t & 15) * 8;
        *(uint4*)(outp + (size_t)(row0 + r) * DD + c8) =
            *(const uint4*)(&Ot[r * 128 + c8]);
    }
}

// ---------------------------------------------------------------------------
// Bucketed CSR build. Pair = (local_dst<<17) | src  packed in one uint.
// Phase A: partition edges into NB buckets.
// ---------------------------------------------------------------------------
__global__ __launch_bounds__(256) void partA(
    const int* __restrict__ src, const int* __restrict__ dst, int E,
    int* __restrict__ bcnt, uint_t* __restrict__ pairs)
{
    __shared__ int hist[NB];
    __shared__ int base[NB];
    const int tid = threadIdx.x;
    const int chunk = (E + gridDim.x - 1) / gridDim.x;
    const int e0 = blockIdx.x * chunk;
    int e1 = e0 + chunk; if (e1 > E) e1 = E;

    for (int b = tid; b < NB; b += 256) hist[b] = 0;
    __syncthreads();
    for (int e = e0 + tid; e < e1; e += 256)
        atomicAdd(&hist[dst[e] >> NPB_SHIFT], 1);
    __syncthreads();
    for (int b = tid; b < NB; b += 256) {
        base[b] = atomicAdd(&bcnt[b], hist[b]);
        hist[b] = 0;
    }
    __syncthreads();
    for (int e = e0 + tid; e < e1; e += 256) {
        int d = dst[e];
        int b = d >> NPB_SHIFT;
        int off = atomicAdd(&hist[b], 1);
        int p = base[b] + off;
        if (p < CAPB)
            pairs[(size_t)b * CAPB + p] =
                ((uint_t)(d & (NPB - 1)) << 17) | (uint_t)src[e];
    }
}

// Exclusive scan over NB bucket totals (single block); clamps totals to CAPB.
__global__ __launch_bounds__(256) void bscan(
    int* __restrict__ bcnt, int* __restrict__ bbase)
{
    __shared__ int lds[256];
    const int tid = threadIdx.x;
    int v = 0;
    if (tid < NB) { v = bcnt[tid]; if (v > CAPB) v = CAPB; }
    lds[tid] = v;
    __syncthreads();
    for (int off = 1; off < 256; off <<= 1) {
        int t = 0;
        if (tid >= off) t = lds[tid - off];
        __syncthreads();
        if (tid >= off) lds[tid] += t;
        __syncthreads();
    }
    if (tid < NB) { bbase[tid] = lds[tid] - v; bcnt[tid] = v; }
}

// Phase B: one block per bucket — local count/scan/place in LDS, then stream
// the finished csr segment out coalesced. Produces counts[] and offs[] too.
__global__ __launch_bounds__(256) void partB(
    const uint_t* __restrict__ pairs, const int* __restrict__ bcnt,
    const int* __restrict__ bbase, int* __restrict__ counts,
    int* __restrict__ offs, int* __restrict__ csr)
{
    __shared__ int cnt[NPB];
    __shared__ int loff[NPB];
    __shared__ int ssc[256];
    __shared__ int image[CAPB];

    const int tid = threadIdx.x;
    const int b   = blockIdx.x;
    const int n0  = b << NPB_SHIFT;
    int nb = NN - n0; if (nb > NPB) nb = NPB;
    const int tot   = bcnt[b];
    const int gbase = bbase[b];
    const uint_t* pb = pairs + (size_t)b * CAPB;

    for (int n = tid; n < NPB; n += 256) cnt[n] = 0;
    __syncthreads();
    for (int i = tid; i < tot; i += 256)
        atomicAdd(&cnt[pb[i] >> 17], 1);
    __syncthreads();

    // exclusive scan of cnt[0..511] with 256 threads
    int a0 = cnt[2 * tid], a1 = cnt[2 * tid + 1];
    int s = a0 + a1;
    ssc[tid] = s;
    __syncthreads();
    for (int off = 1; off < 256; off <<= 1) {
        int t = 0;
        if (tid >= off) t = ssc[tid - off];
        __syncthreads();
        if (tid >= off) ssc[tid] += t;
        __syncthreads();
    }
    int pre = ssc[tid] - s;
    loff[2 * tid]     = pre;
    loff[2 * tid + 1] = pre + a0;
    __syncthreads();

    for (int n = tid; n < nb; n += 256) {
        counts[n0 + n] = cnt[n];
        offs[n0 + n]   = gbase + loff[n];
    }
    for (int n = tid; n < NPB; n += 256) cnt[n] = 0;   // reuse as cursor
    __syncthreads();

    for (int i = tid; i < tot; i += 256) {
        uint_t p = pb[i];
        int ln  = p >> 17;
        int pos = loff[ln] + atomicAdd(&cnt[ln], 1);
        image[pos] = (int)(p & 0x1FFFFu);
    }
    __syncthreads();
    for (int i = tid; i < tot; i += 256) csr[gbase + i] = image[i];
}

// ---------------------------------------------------------------------------
// CSR mean-aggregate over bf16 h: mean[n] = sum(h[src])/max(deg,1), bf16 out.
// ---------------------------------------------------------------------------
__global__ __launch_bounds__(256) void aggregate_bf16(
    const ushort_t* __restrict__ h, const int* __restrict__ csr,
    const int* __restrict__ offs, const int* __restrict__ counts,
    ushort_t* __restrict__ mean, int nn)
{
    int gid  = blockIdx.x * 256 + threadIdx.x;
    int node = gid >> 5;
    if (node >= nn) return;
    int lane  = gid & 31;
    int start = offs[node];
    int cnt   = counts[node];

    float a0 = 0.f, a1 = 0.f, a2 = 0.f, a3 = 0.f;
    int j = 0;
    for (; j + 4 <= cnt; j += 4) {
        int s0 = csr[start + j + 0];
        int s1 = csr[start + j + 1];
        int s2 = csr[start + j + 2];
        int s3 = csr[start + j + 3];
        uint2 v0 = *(const uint2*)(h + (size_t)s0 * DD + lane * 4);
        uint2 v1 = *(const uint2*)(h + (size_t)s1 * DD + lane * 4);
        uint2 v2 = *(const uint2*)(h + (size_t)s2 * DD + lane * 4);
        uint2 v3 = *(const uint2*)(h + (size_t)s3 * DD + lane * 4);
        a0 += bflo(v0.x) + bflo(v1.x) + bflo(v2.x) + bflo(v3.x);
        a1 += bfhi(v0.x) + bfhi(v1.x) + bfhi(v2.x) + bfhi(v3.x);
        a2 += bflo(v0.y) + bflo(v1.y) + bflo(v2.y) + bflo(v3.y);
        a3 += bfhi(v0.y) + bfhi(v1.y) + bfhi(v2.y) + bfhi(v3.y);
    }
    for (; j < cnt; ++j) {
        int s = csr[start + j];
        uint2 v = *(const uint2*)(h + (size_t)s * DD + lane * 4);
        a0 += bflo(v.x); a1 += bfhi(v.x);
        a2 += bflo(v.y); a3 += bfhi(v.y);
    }
    float rinv = 1.0f / (float)(cnt > 1 ? cnt : 1);
    uint2 o;
    o.x = pack2bf(a0 * rinv, a1 * rinv);
    o.y = pack2bf(a2 * rinv, a3 * rinv);
    *(uint2*)(mean + (size_t)node * DD + lane * 4) = o;
}

// ---------------------------------------------------------------------------
// Fused edge scoring on bf16 h3: pos edges then neg edges, one dispatch.
// 32 lanes/edge, fp32 accumulation.
// ---------------------------------------------------------------------------
__global__ __launch_bounds__(256) void score_both(
    const ushort_t* __restrict__ h,
    const int* __restrict__ ps, const int* __restrict__ pd,
    const int* __restrict__ ns, const int* __restrict__ nd,
    float* __restrict__ out, int EP, int TE)
{
    int gid = blockIdx.x * 256 + threadIdx.x;
    int e = gid >> 5;
    if (e >= TE) return;
    int lane = gid & 31;
    int si, di;
    if (e < EP) { si = ps[e]; di = pd[e]; }
    else        { si = ns[e - EP]; di = nd[e - EP]; }
    uint2 a = *(const uint2*)(h + (size_t)si * DD + lane * 4);
    uint2 b = *(const uint2*)(h + (size_t)di * DD + lane * 4);
    float s = bflo(a.x) * bflo(b.x) + bfhi(a.x) * bfhi(b.x)
            + bflo(a.y) * bflo(b.y) + bfhi(a.y) * bfhi(b.y);
#pragma unroll
    for (int off = 16; off; off >>= 1) s += __shfl_down(s, off, 32);
    if (lane == 0) out[e] = s;
}

// ---------------------------------------------------------------------------

static void build_csr_and_aggregate(const ushort_t* h, const int* esrc,
                                    const int* edst, int E,
                                    uint_t* pairs, int* bcnt, int* bbase,
                                    int* counts, int* offs, int* csr,
                                    ushort_t* mean, hipStream_t stream)
{
    hipMemsetAsync(bcnt, 0, NB * sizeof(int), stream);
    partA<<<NB, 256, 0, stream>>>(esrc, edst, E, bcnt, pairs);
    bscan<<<1, 256, 0, stream>>>(bcnt, bbase);
    partB<<<NB, 256, 0, stream>>>(pairs, bcnt, bbase, counts, offs, csr);
    aggregate_bf16<<<(NN * 32 + 255) / 256, 256, 0, stream>>>(
        h, csr, offs, counts, mean, NN);
}

extern "C" void kernel_launch(void* const* d_in, const int* in_sizes, int n_in,
                              void* d_out, int out_size, void* d_ws, size_t ws_size,
                              hipStream_t stream)
{
    const float* feat    = (const float*)d_in[0];
    const int*   e0s     = (const int*)d_in[1];
    const int*   e0d     = (const int*)d_in[2];
    const int*   e1s     = (const int*)d_in[3];
    const int*   e1d     = (const int*)d_in[4];
    const int*   ps      = (const int*)d_in[5];
    const int*   pd      = (const int*)d_in[6];
    const int*   ns      = (const int*)d_in[7];
    const int*   nd      = (const int*)d_in[8];
    const float* w_proj  = (const float*)d_in[9];
    const float* b_proj  = (const float*)d_in[10];
    const float* w_self1 = (const float*)d_in[11];
    const float* w_neigh1= (const float*)d_in[12];
    const float* b1      = (const float*)d_in[13];
    const float* w_self2 = (const float*)d_in[14];
    const float* w_neigh2= (const float*)d_in[15];
    const float* b2      = (const float*)d_in[16];

    float* out = (float*)d_out;

    const size_t NF = (size_t)NN * DD;
    char* base = (char*)d_ws;

    // bf16 buffers, NF*2 bytes each. featb dies after layer-0 gemm; h3
    // reuses its slot.
    ushort_t* featb = (ushort_t*)base;
    ushort_t* h3    = (ushort_t*)base;
    ushort_t* h1    = (ushort_t*)(base + NF * 2);
    ushort_t* mean  = (ushort_t*)(base + NF * 4);
    ushort_t* h2    = (ushort_t*)(base + NF * 6);

    uint_t* pairs = (uint_t*)(base + NF * 8);                // NB*CAPB*4 B
    int*    ints  = (int*)((char*)pairs + (size_t)NB * CAPB * 4);
    int* counts = ints;                  // [NN]
    int* offs   = ints + NN;             // [NN]
    int* csr    = ints + 2 * NN;         // [1.6M]
    int* bcnt   = ints + 2 * NN + 1600000;
    int* bbase  = bcnt + 256;
    ushort_t* wts = (ushort_t*)(bbase + 256);
    ushort_t* wtp = wts;                 // [128][128]
    ushort_t* wt1 = wts + 128 * 128;     // [128][256]
    ushort_t* wt2 = wt1 + 128 * 256;     // [128][256]

    const int E0 = in_sizes[1];
    const int E1 = in_sizes[3];
    const int EP = in_sizes[5];
    const int EN = in_sizes[7];

    const int GB = (NN + 127) / 128;     // 782

    // ---- Prep
    convert_feat<<<(int)(NF / 8 / 256), 256, 0, stream>>>(feat, featb);
    prep_w<<<64, 256, 0, stream>>>(w_proj,   wtp, 128, 0);
    prep_w<<<64, 256, 0, stream>>>(w_self1,  wt1, 256, 0);
    prep_w<<<64, 256, 0, stream>>>(w_neigh1, wt1, 256, 128);
    prep_w<<<64, 256, 0, stream>>>(w_self2,  wt2, 256, 0);
    prep_w<<<64, 256, 0, stream>>>(w_neigh2, wt2, 256, 128);

    // ---- Layer 0: h1 = relu(feat @ w_proj + b_proj)
    gemm_bf16<true, false><<<GB, 256, 0, stream>>>(
        featb, nullptr, wtp, b_proj, h1);

    // ---- Layer 1
    build_csr_and_aggregate(h1, e0s, e0d, E0, pairs, bcnt, bbase,
                            counts, offs, csr, mean, stream);
    gemm_bf16<true, true><<<GB, 256, 0, stream>>>(
        h1, mean, wt1, b1, h2);

    // ---- Layer 2 (h3 overwrites featb slot — featb is dead by now)
    build_csr_and_aggregate(h2, e1s, e1d, E1, pairs, bcnt, bbase,
                            counts, offs, csr, mean, stream);
    gemm_bf16<false, true><<<GB, 256, 0, stream>>>(
        h2, mean, wt2, b2, h3);

    // ---- Fused scoring on bf16 h3
    const int TE = EP + EN;
    score_both<<<(TE * 32 + 255) / 256, 256, 0, stream>>>(
        h3, ps, pd, ns, nd, out, EP, TE);
}